// Round 12
// baseline (220.519 us; speedup 1.0000x reference)
//
#include <hip/hip_runtime.h>
#include <stdint.h>

#define BN 4096
#define DD 128
#define EPSF 1e-6f
#define MARGINF 1.0f

typedef unsigned long long ull;
typedef unsigned short ushort;
typedef short short8 __attribute__((ext_vector_type(8)));
typedef float f32x4 __attribute__((ext_vector_type(4)));

__device__ __forceinline__ unsigned int ord_f32(float f) {
    unsigned int u = __float_as_uint(f);
    return (u & 0x80000000u) ? ~u : (u | 0x80000000u);
}
__device__ __forceinline__ ushort bf16_rne(float x) {
    unsigned int u = __float_as_uint(x);
    return (ushort)((u + 0x7FFFu + ((u >> 16) & 1u)) >> 16);
}

// --- prep: row stats + inv perm + key init + bf16 convert of e ---
__global__ void k_prep(const float* __restrict__ e, const int* __restrict__ tidx,
                       float* __restrict__ sq, float* __restrict__ s,
                       int* __restrict__ inv, ull* __restrict__ pk, ull* __restrict__ nk,
                       unsigned int* __restrict__ ehi) {
    int w = threadIdx.x >> 6, lane = threadIdx.x & 63;
    int row = blockIdx.x * 4 + w;
    float2 v = ((const float2*)(e + (size_t)row * DD))[lane];
    ushort hx = bf16_rne(v.x), hy = bf16_rne(v.y);
    ehi[row * 64 + lane] = (unsigned int)hx | ((unsigned int)hy << 16);
    float ss = v.x + v.y;
    float qq = v.x * v.x + v.y * v.y;
    #pragma unroll
    for (int off = 32; off > 0; off >>= 1) {
        ss += __shfl_down(ss, off);
        qq += __shfl_down(qq, off);
    }
    if (lane == 0) {
        sq[row] = qq; s[row] = ss;
        inv[tidx[row]] = row;
        pk[row] = 0ULL; nk[row] = 0ULL;   // both max-merged (neg uses inverted keys)
    }
}

// --- fused producer/consumer: waves 0-3 MFMA 128x128 tile, waves 4-7 stream masks ---
__global__ __launch_bounds__(512)
void k_select(const ushort* __restrict__ ehi,
              const int* __restrict__ pos, const int* __restrict__ neg,
              const float* __restrict__ sq, const float* __restrict__ s,
              const int* __restrict__ inv,
              ull* __restrict__ pkey, ull* __restrict__ nkey) {
    // smem: B staging [2 kc][128 r][72 pad] ushorts = 36 KB;
    //       after K-loop aliased: [4K,20K) scrp[16][128], [20K,36K) scrn[16][128]
    __shared__ __align__(16) char smem[36864];
    __shared__ ull pbl[256], nbl[256];      // dedicated 4 KB (producer-written)
    __shared__ float rjl[128];
    __shared__ int jvs[128];

    ushort* Bst = (ushort*)smem;

    const int tid = threadIdx.x;
    const int lane = tid & 63;
    const int w = tid >> 6, wr = w >> 1, wc = w & 1;   // consumer wave coords (w<4)
    const int lrow = lane & 15, quad = lane >> 4;
    const int i0 = blockIdx.x * 128, c0 = blockIdx.y * 128;

    if (tid < 128) {
        int j = inv[c0 + tid];
        jvs[tid] = j;
        rjl[tid] = sq[j] - 2.0f * EPSF * s[j];
    }
    __syncthreads();   // 1: jvs visible

    if (tid < 256) {
        // consumers: stage B (128 gathered rows x 256 B), once for all K
        #pragma unroll
        for (int it = 0; it < 8; it++) {
            int slot = it * 256 + tid;
            int r = slot >> 4, seg16 = slot & 15;
            int kc = seg16 >> 3, seg = seg16 & 7;
            int jr = jvs[r];
            int4 v = ((const int4*)ehi)[(size_t)jr * 16 + seg16];
            *(int4*)(Bst + (kc * 128 + r) * 72 + seg * 8) = v;
        }
    }
    __syncthreads();   // 2: B staged; producers start streaming now

    f32x4 acc[4][4];
    if (tid < 256) {
        // ---- consumer K-loop: MFMA, A direct from global, B from LDS ----
        #pragma unroll
        for (int rt = 0; rt < 4; rt++)
            #pragma unroll
            for (int ct = 0; ct < 4; ct++)
                acc[rt][ct] = (f32x4){0.f, 0.f, 0.f, 0.f};
        size_t abase[4];
        #pragma unroll
        for (int rt = 0; rt < 4; rt++)
            abase[rt] = (size_t)(i0 + wr * 64 + rt * 16 + lrow) * DD + quad * 8;
        #pragma unroll
        for (int ks = 0; ks < 4; ks++) {
            const int kc = ks >> 1, ksl = ks & 1;
            short8 ah[4];
            #pragma unroll
            for (int rt = 0; rt < 4; rt++)
                ah[rt] = *(const short8*)(ehi + abase[rt] + ks * 32);
            #pragma unroll
            for (int ct = 0; ct < 4; ct++) {
                const int bo = (kc * 128 + wc * 64 + ct * 16 + lrow) * 72 + ksl * 32 + quad * 8;
                short8 bh = *(const short8*)(Bst + bo);
                #pragma unroll
                for (int rt = 0; rt < 4; rt++)
                    acc[rt][ct] = __builtin_amdgcn_mfma_f32_16x16x32_bf16(ah[rt], bh, acc[rt][ct], 0, 0, 0);
            }
        }
    } else {
        // ---- producer waves: stream this block's 128x128 mask tile -> pbl/nbl ----
        // thread t2 owns (row = t2>>1, half = t2&1): 64 cols -> one 64-bit word each mask
        const int t2 = tid - 256;
        const int r = t2 >> 1, h = t2 & 1;
        const int4* pr4 = (const int4*)(pos + (size_t)(i0 + r) * BN + c0 + h * 64);
        const int4* nr4 = (const int4*)(neg + (size_t)(i0 + r) * BN + c0 + h * 64);
        ull pw = 0ULL, nw = 0ULL;
        #pragma unroll
        for (int g = 0; g < 16; g++) {
            int4 P = pr4[g];
            int4 N = nr4[g];
            unsigned int pm = (unsigned int)(P.x != 0) | ((unsigned int)(P.y != 0) << 1)
                            | ((unsigned int)(P.z != 0) << 2) | ((unsigned int)(P.w != 0) << 3);
            unsigned int nm = (unsigned int)(N.x != 0) | ((unsigned int)(N.y != 0) << 1)
                            | ((unsigned int)(N.z != 0) << 2) | ((unsigned int)(N.w != 0) << 3);
            pw |= ((ull)pm) << (g * 4);
            nw |= ((ull)nm) << (g * 4);
        }
        pbl[t2] = pw;     // layout: pbl[row*2 + half] — matches epilogue
        nbl[t2] = nw;
    }
    __syncthreads();   // 3: K-loop done AND masks in LDS; alias region safe

    ull* scrp = (ull*)(smem + 4096);        // [16][128]
    ull* scrn = (ull*)(smem + 20480);       // [16][128]
    if (tid < 256) {
        // selection on m = rj - 2*dot (row-constant terms dropped; per-row order identical)
        int jcol[4]; float rjc[4];
        #pragma unroll
        for (int ct = 0; ct < 4; ct++) {
            jcol[ct] = jvs[wc * 64 + ct * 16 + lrow];
            rjc[ct] = rjl[wc * 64 + ct * 16 + lrow];
        }
        #pragma unroll
        for (int rt = 0; rt < 4; rt++)
            #pragma unroll
            for (int t = 0; t < 4; t++) {
                const int row = wr * 64 + rt * 16 + quad * 4 + t;
                ull pb = pbl[row * 2 + wc] >> lrow;
                ull nb = nbl[row * 2 + wc] >> lrow;
                float bpv = -3.4e38f, bnv = 3.4e38f;
                int bpi = 0x7FFFFFFF, bni = 0x7FFFFFFF;
                #pragma unroll
                for (int ct = 0; ct < 4; ct++) {
                    float m = rjc[ct] - 2.0f * acc[rt][ct][t];
                    int j = jcol[ct];
                    if ((pb >> (ct * 16)) & 1ULL) {
                        if (m > bpv || (m == bpv && j < bpi)) { bpv = m; bpi = j; }
                    }
                    if ((nb >> (ct * 16)) & 1ULL) {
                        if (m < bnv || (m == bnv && j < bni)) { bnv = m; bni = j; }
                    }
                }
                ull kp = (bpi == 0x7FFFFFFF) ? 0ULL
                       : (((ull)ord_f32(bpv) << 32) | (ull)(0xFFFFFFFFu - (unsigned)bpi));
                ull kn = (bni == 0x7FFFFFFF) ? 0ULL
                       : (((ull)(~ord_f32(bnv)) << 32) | (ull)(0xFFFFFFFFu - (unsigned)bni));
                ull op = __shfl_xor(kp, 8); if (op > kp) kp = op;   // fold lrow with lrow^8
                ull on = __shfl_xor(kn, 8); if (on > kn) kn = on;
                if (lrow < 8) {
                    scrp[(wc * 8 + lrow) * 128 + row] = kp;   // [k][row]: conflict-free read
                    scrn[(wc * 8 + lrow) * 128 + row] = kn;
                }
            }
    }
    __syncthreads();   // 4
    if (tid < 128) {
        ull kp = 0ULL, kn = 0ULL;
        #pragma unroll
        for (int k = 0; k < 16; k++) {
            ull v = scrp[k * 128 + tid]; if (v > kp) kp = v;
            v = scrn[k * 128 + tid];     if (v > kn) kn = v;
        }
        if (kp) atomicMax(&pkey[i0 + tid], kp);
        if (kn) atomicMax(&nkey[i0 + tid], kn);
    }
}

// --- per-row triplet loss: wave per row (coalesced), block partials ---
__global__ void k_loss(const float* __restrict__ e,
                       const ull* __restrict__ pkey, const ull* __restrict__ nkey,
                       float* __restrict__ partials) {
    int w = threadIdx.x >> 6, lane = threadIdx.x & 63;
    int row = blockIdx.x * 4 + w;
    ull pk = pkey[row], nk = nkey[row];
    float loss = 0.0f, wt = 0.0f;
    if (pk != 0ULL && nk != 0ULL) {
        int pi = (int)(0xFFFFFFFFu - (unsigned)(pk & 0xFFFFFFFFu));
        int ni = (int)(0xFFFFFFFFu - (unsigned)(nk & 0xFFFFFFFFu));
        float2 av = ((const float2*)(e + (size_t)row * DD))[lane];
        float2 pv = ((const float2*)(e + (size_t)pi * DD))[lane];
        float2 nv = ((const float2*)(e + (size_t)ni * DD))[lane];
        float dx, dy;
        dx = av.x - pv.x + EPSF; dy = av.y - pv.y + EPSF;
        float ap2 = dx * dx + dy * dy;
        dx = av.x - nv.x + EPSF; dy = av.y - nv.y + EPSF;
        float an2 = dx * dx + dy * dy;
        dx = pv.x - nv.x + EPSF; dy = pv.y - nv.y + EPSF;
        float pn2 = dx * dx + dy * dy;
        #pragma unroll
        for (int off = 32; off > 0; off >>= 1) {
            ap2 += __shfl_down(ap2, off);
            an2 += __shfl_down(an2, off);
            pn2 += __shfl_down(pn2, off);
        }
        if (lane == 0) {
            float ap = sqrtf(ap2), an = sqrtf(an2), pn = sqrtf(pn2);
            loss = fmaxf(ap - fminf(an, pn) + MARGINF, 0.0f);
            wt = 1.0f;
        }
    }
    __shared__ float sl[4], sw[4];
    if (lane == 0) { sl[w] = loss; sw[w] = wt; }
    __syncthreads();
    if (threadIdx.x == 0) {
        partials[blockIdx.x * 2 + 0] = sl[0] + sl[1] + sl[2] + sl[3];
        partials[blockIdx.x * 2 + 1] = sw[0] + sw[1] + sw[2] + sw[3];
    }
}

// --- finalize ---
__global__ void k_final(const float* __restrict__ partials, float* __restrict__ out) {
    int tid = threadIdx.x;
    float L = 0.0f, W = 0.0f;
    for (int i = 0; i < 4; i++) {
        int idx = tid + i * 256;
        L += partials[idx * 2];
        W += partials[idx * 2 + 1];
    }
    #pragma unroll
    for (int off = 32; off > 0; off >>= 1) {
        L += __shfl_down(L, off);
        W += __shfl_down(W, off);
    }
    __shared__ float sl[4], sw[4];
    int w = tid >> 6, lane = tid & 63;
    if (lane == 0) { sl[w] = L; sw[w] = W; }
    __syncthreads();
    if (tid == 0) {
        float Lt = sl[0] + sl[1] + sl[2] + sl[3];
        float Wt = sw[0] + sw[1] + sw[2] + sw[3];
        out[0] = Lt / fmaxf(Wt, 1.0f);
    }
}

extern "C" void kernel_launch(void* const* d_in, const int* in_sizes, int n_in,
                              void* d_out, int out_size, void* d_ws, size_t ws_size,
                              hipStream_t stream) {
    const float* e    = (const float*)d_in[0];
    const int*   tidx = (const int*)d_in[1];
    const int*   pos  = (const int*)d_in[2];
    const int*   neg  = (const int*)d_in[3];
    float* out = (float*)d_out;

    ull* pkey  = (ull*)d_ws;                  // 4096
    ull* nkey  = pkey + BN;                   // 4096
    float* sq  = (float*)(nkey + BN);
    float* s   = sq + BN;
    int* inv   = (int*)(s + BN);
    float* partials = (float*)(inv + BN);     // 2048
    unsigned int* ehi = (unsigned int*)(partials + 2048);  // 4096*64 uints

    k_prep<<<BN / 4, 256, 0, stream>>>(e, tidx, sq, s, inv, pkey, nkey, ehi);
    dim3 grid(BN / 128, BN / 128);
    k_select<<<grid, 512, 0, stream>>>((const ushort*)ehi, pos, neg,
                                       sq, s, inv, pkey, nkey);
    k_loss<<<BN / 4, 256, 0, stream>>>(e, pkey, nkey, partials);
    k_final<<<1, 256, 0, stream>>>(partials, out);
}

// Round 13
// 184.288 us; speedup vs baseline: 1.1966x; 1.1966x over previous
//
#include <hip/hip_runtime.h>
#include <stdint.h>

#define BN 4096
#define DD 128
#define EPSF 1e-6f
#define MARGINF 1.0f

typedef unsigned long long ull;
typedef unsigned short ushort;
typedef short short8 __attribute__((ext_vector_type(8)));
typedef float f32x4 __attribute__((ext_vector_type(4)));

__device__ __forceinline__ unsigned int ord_f32(float f) {
    unsigned int u = __float_as_uint(f);
    return (u & 0x80000000u) ? ~u : (u | 0x80000000u);
}
__device__ __forceinline__ ushort bf16_rne(float x) {
    unsigned int u = __float_as_uint(x);
    return (ushort)((u + 0x7FFFu + ((u >> 16) & 1u)) >> 16);
}
// 8 bytes (low nibbles valid) -> 32-bit packed nibbles
__device__ __forceinline__ unsigned int pack8(ull v) {
    v &= 0x0F0F0F0F0F0F0F0FULL;
    v = (v | (v >> 4)) & 0x00FF00FF00FF00FFULL;
    v = (v | (v >> 8)) & 0x0000FFFF0000FFFFULL;
    v = (v | (v >> 16));
    return (unsigned int)v;
}

// --- prep: row stats + inv perm + key init + bf16 convert of e ---
__global__ void k_prep(const float* __restrict__ e, const int* __restrict__ tidx,
                       float* __restrict__ sq, float* __restrict__ s,
                       int* __restrict__ inv, ull* __restrict__ pk, ull* __restrict__ nk,
                       unsigned int* __restrict__ ehi) {
    int w = threadIdx.x >> 6, lane = threadIdx.x & 63;
    int row = blockIdx.x * 4 + w;
    float2 v = ((const float2*)(e + (size_t)row * DD))[lane];
    ushort hx = bf16_rne(v.x), hy = bf16_rne(v.y);
    ehi[row * 64 + lane] = (unsigned int)hx | ((unsigned int)hy << 16);
    float ss = v.x + v.y;
    float qq = v.x * v.x + v.y * v.y;
    #pragma unroll
    for (int off = 32; off > 0; off >>= 1) {
        ss += __shfl_down(ss, off);
        qq += __shfl_down(qq, off);
    }
    if (lane == 0) {
        sq[row] = qq; s[row] = ss;
        inv[tidx[row]] = row;
        pk[row] = 0ULL; nk[row] = 0ULL;   // both max-merged (neg uses inverted keys)
    }
}

// --- fused: mask tile compress + bf16 MFMA + selection; 128x128 tile ---
__global__ __launch_bounds__(256, 4)
void k_select(const ushort* __restrict__ ehi,
              const int* __restrict__ pos, const int* __restrict__ neg,
              const float* __restrict__ sq, const float* __restrict__ s,
              const int* __restrict__ inv,
              ull* __restrict__ pkey, ull* __restrict__ nkey) {
    // smem phases:
    //  phase1: [0,4K) nibP[128][32], [4K,8K) nibN[128][32]
    //  phase2: B staging [2 kc][128 r][72] ushorts = 36 KB
    //  phase3: [0,2K) pbl[256], [2K,4K) nbl[256], [4K,20K) scrp, [20K,36K) scrn
    __shared__ __align__(16) char smem[36864];
    __shared__ float rjl[128];
    __shared__ int jvs[128];

    const int tid = threadIdx.x;
    const int lane = tid & 63;
    const int w = tid >> 6, wr = w >> 1, wc = w & 1;
    const int lrow = lane & 15, quad = lane >> 4;
    const int i0 = blockIdx.x * 128, c0 = blockIdx.y * 128;

    if (tid < 128) {
        int j = inv[c0 + tid];
        jvs[tid] = j;
        rjl[tid] = sq[j] - 2.0f * EPSF * s[j];
    }

    // phase 1: coalesced mask tile loads -> nibbles in LDS
    unsigned char* nibP = (unsigned char*)smem;
    unsigned char* nibN = (unsigned char*)(smem + 4096);
    {
        const int4* pbase = (const int4*)(pos + (size_t)i0 * BN + c0);
        const int4* nbase = (const int4*)(neg + (size_t)i0 * BN + c0);
        #pragma unroll
        for (int p = 0; p < 16; p++) {
            int flat = p * 256 + tid;
            int r = flat >> 5, q = flat & 31;        // row r, int4-index q (4 cols)
            size_t idx = (size_t)r * (BN / 4) + q;
            int4 P = pbase[idx];
            int4 N = nbase[idx];
            unsigned int pm = (unsigned int)(P.x != 0) | ((unsigned int)(P.y != 0) << 1)
                            | ((unsigned int)(P.z != 0) << 2) | ((unsigned int)(P.w != 0) << 3);
            unsigned int nm = (unsigned int)(N.x != 0) | ((unsigned int)(N.y != 0) << 1)
                            | ((unsigned int)(N.z != 0) << 2) | ((unsigned int)(N.w != 0) << 3);
            nibP[r * 32 + q] = (unsigned char)pm;
            nibN[r * 32 + q] = (unsigned char)nm;
        }
    }
    __syncthreads();

    // pack this thread's (row = tid>>1, half = tid&1) 64-bit mask words into regs
    ull pw, nw;
    {
        int off = (tid >> 1) * 32 + (tid & 1) * 16;
        ull lo = *(const ull*)(nibP + off);
        ull hi = *(const ull*)(nibP + off + 8);
        pw = (ull)pack8(lo) | ((ull)pack8(hi) << 32);
        lo = *(const ull*)(nibN + off);
        hi = *(const ull*)(nibN + off + 8);
        nw = (ull)pack8(lo) | ((ull)pack8(hi) << 32);
    }
    __syncthreads();   // nib reads done; jvs visible; B staging may overwrite

    // phase 2: stage B (gathered rows) once for all K
    ushort* Bst = (ushort*)smem;
    #pragma unroll
    for (int it = 0; it < 8; it++) {
        int slot = it * 256 + tid;
        int r = slot >> 4, seg16 = slot & 15;
        int kc = seg16 >> 3, seg = seg16 & 7;
        int jr = jvs[r];
        int4 v = ((const int4*)ehi)[(size_t)jr * 16 + seg16];
        *(int4*)(Bst + (kc * 128 + r) * 72 + seg * 8) = v;
    }
    __syncthreads();

    f32x4 acc[4][4];
    #pragma unroll
    for (int rt = 0; rt < 4; rt++)
        #pragma unroll
        for (int ct = 0; ct < 4; ct++)
            acc[rt][ct] = (f32x4){0.f, 0.f, 0.f, 0.f};

    size_t abase[4];
    #pragma unroll
    for (int rt = 0; rt < 4; rt++)
        abase[rt] = (size_t)(i0 + wr * 64 + rt * 16 + lrow) * DD + quad * 8;

    // K-loop: no barriers; A direct from global (L2-resident), B from LDS
    #pragma unroll
    for (int ks = 0; ks < 4; ks++) {
        const int kc = ks >> 1, ksl = ks & 1;
        short8 ah[4];
        #pragma unroll
        for (int rt = 0; rt < 4; rt++)
            ah[rt] = *(const short8*)(ehi + abase[rt] + ks * 32);
        #pragma unroll
        for (int ct = 0; ct < 4; ct++) {
            const int bo = (kc * 128 + wc * 64 + ct * 16 + lrow) * 72 + ksl * 32 + quad * 8;
            short8 bh = *(const short8*)(Bst + bo);
            #pragma unroll
            for (int rt = 0; rt < 4; rt++)
                acc[rt][ct] = __builtin_amdgcn_mfma_f32_16x16x32_bf16(ah[rt], bh, acc[rt][ct], 0, 0, 0);
        }
    }

    __syncthreads();   // B reads done; alias region now safe
    ull* pbl = (ull*)smem;                  // [128][2]
    ull* nbl = (ull*)(smem + 2048);
    pbl[tid] = pw;
    nbl[tid] = nw;
    __syncthreads();

    // selection on m = rj - 2*dot (row-constant terms dropped; per-row order identical)
    int jcol[4]; float rjc[4];
    #pragma unroll
    for (int ct = 0; ct < 4; ct++) {
        jcol[ct] = jvs[wc * 64 + ct * 16 + lrow];
        rjc[ct] = rjl[wc * 64 + ct * 16 + lrow];
    }
    ull* scrp = (ull*)(smem + 4096);        // [16][128]
    ull* scrn = (ull*)(smem + 20480);       // [16][128]
    #pragma unroll
    for (int rt = 0; rt < 4; rt++)
        #pragma unroll
        for (int t = 0; t < 4; t++) {
            const int row = wr * 64 + rt * 16 + quad * 4 + t;
            ull pb = pbl[row * 2 + wc] >> lrow;
            ull nb = nbl[row * 2 + wc] >> lrow;
            float bpv = -3.4e38f, bnv = 3.4e38f;
            int bpi = 0x7FFFFFFF, bni = 0x7FFFFFFF;
            #pragma unroll
            for (int ct = 0; ct < 4; ct++) {
                float m = rjc[ct] - 2.0f * acc[rt][ct][t];
                int j = jcol[ct];
                if ((pb >> (ct * 16)) & 1ULL) {
                    if (m > bpv || (m == bpv && j < bpi)) { bpv = m; bpi = j; }
                }
                if ((nb >> (ct * 16)) & 1ULL) {
                    if (m < bnv || (m == bnv && j < bni)) { bnv = m; bni = j; }
                }
            }
            ull kp = (bpi == 0x7FFFFFFF) ? 0ULL
                   : (((ull)ord_f32(bpv) << 32) | (ull)(0xFFFFFFFFu - (unsigned)bpi));
            ull kn = (bni == 0x7FFFFFFF) ? 0ULL
                   : (((ull)(~ord_f32(bnv)) << 32) | (ull)(0xFFFFFFFFu - (unsigned)bni));
            ull op = __shfl_xor(kp, 8); if (op > kp) kp = op;   // fold lrow with lrow^8
            ull on = __shfl_xor(kn, 8); if (on > kn) kn = on;
            if (lrow < 8) {
                scrp[(wc * 8 + lrow) * 128 + row] = kp;   // [k][row]: conflict-free read
                scrn[(wc * 8 + lrow) * 128 + row] = kn;
            }
        }
    __syncthreads();
    if (tid < 128) {
        ull kp = 0ULL, kn = 0ULL;
        #pragma unroll
        for (int k = 0; k < 16; k++) {
            ull v = scrp[k * 128 + tid]; if (v > kp) kp = v;
            v = scrn[k * 128 + tid];     if (v > kn) kn = v;
        }
        if (kp) atomicMax(&pkey[i0 + tid], kp);
        if (kn) atomicMax(&nkey[i0 + tid], kn);
    }
}

// --- per-row triplet loss: wave per row (coalesced), block partials ---
__global__ void k_loss(const float* __restrict__ e,
                       const ull* __restrict__ pkey, const ull* __restrict__ nkey,
                       float* __restrict__ partials) {
    int w = threadIdx.x >> 6, lane = threadIdx.x & 63;
    int row = blockIdx.x * 4 + w;
    ull pk = pkey[row], nk = nkey[row];
    float loss = 0.0f, wt = 0.0f;
    if (pk != 0ULL && nk != 0ULL) {
        int pi = (int)(0xFFFFFFFFu - (unsigned)(pk & 0xFFFFFFFFu));
        int ni = (int)(0xFFFFFFFFu - (unsigned)(nk & 0xFFFFFFFFu));
        float2 av = ((const float2*)(e + (size_t)row * DD))[lane];
        float2 pv = ((const float2*)(e + (size_t)pi * DD))[lane];
        float2 nv = ((const float2*)(e + (size_t)ni * DD))[lane];
        float dx, dy;
        dx = av.x - pv.x + EPSF; dy = av.y - pv.y + EPSF;
        float ap2 = dx * dx + dy * dy;
        dx = av.x - nv.x + EPSF; dy = av.y - nv.y + EPSF;
        float an2 = dx * dx + dy * dy;
        dx = pv.x - nv.x + EPSF; dy = pv.y - nv.y + EPSF;
        float pn2 = dx * dx + dy * dy;
        #pragma unroll
        for (int off = 32; off > 0; off >>= 1) {
            ap2 += __shfl_down(ap2, off);
            an2 += __shfl_down(an2, off);
            pn2 += __shfl_down(pn2, off);
        }
        if (lane == 0) {
            float ap = sqrtf(ap2), an = sqrtf(an2), pn = sqrtf(pn2);
            loss = fmaxf(ap - fminf(an, pn) + MARGINF, 0.0f);
            wt = 1.0f;
        }
    }
    __shared__ float sl[4], sw[4];
    if (lane == 0) { sl[w] = loss; sw[w] = wt; }
    __syncthreads();
    if (threadIdx.x == 0) {
        partials[blockIdx.x * 2 + 0] = sl[0] + sl[1] + sl[2] + sl[3];
        partials[blockIdx.x * 2 + 1] = sw[0] + sw[1] + sw[2] + sw[3];
    }
}

// --- finalize ---
__global__ void k_final(const float* __restrict__ partials, float* __restrict__ out) {
    int tid = threadIdx.x;
    float L = 0.0f, W = 0.0f;
    for (int i = 0; i < 4; i++) {
        int idx = tid + i * 256;
        L += partials[idx * 2];
        W += partials[idx * 2 + 1];
    }
    #pragma unroll
    for (int off = 32; off > 0; off >>= 1) {
        L += __shfl_down(L, off);
        W += __shfl_down(W, off);
    }
    __shared__ float sl[4], sw[4];
    int w = tid >> 6, lane = tid & 63;
    if (lane == 0) { sl[w] = L; sw[w] = W; }
    __syncthreads();
    if (tid == 0) {
        float Lt = sl[0] + sl[1] + sl[2] + sl[3];
        float Wt = sw[0] + sw[1] + sw[2] + sw[3];
        out[0] = Lt / fmaxf(Wt, 1.0f);
    }
}

extern "C" void kernel_launch(void* const* d_in, const int* in_sizes, int n_in,
                              void* d_out, int out_size, void* d_ws, size_t ws_size,
                              hipStream_t stream) {
    const float* e    = (const float*)d_in[0];
    const int*   tidx = (const int*)d_in[1];
    const int*   pos  = (const int*)d_in[2];
    const int*   neg  = (const int*)d_in[3];
    float* out = (float*)d_out;

    ull* pkey  = (ull*)d_ws;                  // 4096
    ull* nkey  = pkey + BN;                   // 4096
    float* sq  = (float*)(nkey + BN);
    float* s   = sq + BN;
    int* inv   = (int*)(s + BN);
    float* partials = (float*)(inv + BN);     // 2048
    unsigned int* ehi = (unsigned int*)(partials + 2048);  // 4096*64 uints

    k_prep<<<BN / 4, 256, 0, stream>>>(e, tidx, sq, s, inv, pkey, nkey, ehi);
    dim3 grid(BN / 128, BN / 128);
    k_select<<<grid, 256, 0, stream>>>((const ushort*)ehi, pos, neg,
                                       sq, s, inv, pkey, nkey);
    k_loss<<<BN / 4, 256, 0, stream>>>(e, pkey, nkey, partials);
    k_final<<<1, 256, 0, stream>>>(partials, out);
}